// Round 9
// baseline (661.736 us; speedup 1.0000x reference)
//
#include <hip/hip_runtime.h>
#include <hip/hip_cooperative_groups.h>
#include <stdint.h>

namespace cg = cooperative_groups;

#define B_DIM 8192
#define D_DIM 1024
#define N_DIM 4096
#define ND ((size_t)N_DIM * D_DIM)
#define LRc 0.02f
#define ATc 0.3f
#define EMAc (0.02f * 0.1f)   // LR*DSBETA = 0.002
#define QS 32.0f              // i8 quant scale
#define INV_QS2 (1.0f / (QS * QS))
#define MARGIN_G 10.0f        // candidate window in g-units (>>sigma of i8-quant + u8-residual error)
#define NBLK 512              // cooperative grid: 2 blocks/CU (LDS 32KB, VGPR+AGPR <= 256)

typedef int intv4 __attribute__((ext_vector_type(4)));

__device__ __forceinline__ void async16(void* lds, const void* g) {
    __builtin_amdgcn_global_load_lds((const __attribute__((address_space(1))) void*)g,
                                     (__attribute__((address_space(3))) void*)lds, 16, 0, 0);
}

__device__ __forceinline__ int q8(float v) {
    return (int)rintf(fminf(fmaxf(v * QS, -127.0f), 127.0f));
}

__device__ __forceinline__ unsigned pack4(float4 v) {
    return (unsigned)(q8(v.x) & 255) | ((unsigned)(q8(v.y) & 255) << 8)
         | ((unsigned)(q8(v.z) & 255) << 16) | ((unsigned)(q8(v.w) & 255) << 24);
}

// ======================= device phase bodies (shared by fused + fallback) =======================

__device__ __forceinline__ void prep_row(int row, const float* x, const float* w, const float* rel,
                                         signed char* xq, signed char* wq,
                                         float* x2p, float* w2p, float* rsump, float* gbp, int lane) {
    if (row < B_DIM) {
        const float4* xr = (const float4*)(x + (size_t)row * D_DIM);
        unsigned* xqr = (unsigned*)(xq + (size_t)row * D_DIM);
        float ss = 0.f;
#pragma unroll
        for (int j = 0; j < 4; ++j) {
            const float4 v = xr[lane + j * 64];
            ss += v.x * v.x + v.y * v.y + v.z * v.z + v.w * v.w;
            xqr[lane + j * 64] = pack4(v);
        }
#pragma unroll
        for (int o = 32; o; o >>= 1) ss += __shfl_xor(ss, o);
        if (lane == 0) x2p[row] = ss;
    } else {
        const int n = row - B_DIM;
        const float4* wr = (const float4*)(w + (size_t)n * D_DIM);
        const float4* rr = (const float4*)(rel + (size_t)n * D_DIM);
        unsigned* wqr = (unsigned*)(wq + (size_t)n * D_DIM);
        float ss = 0.f, rs = 0.f;
#pragma unroll
        for (int j = 0; j < 4; ++j) {
            const float4 v = wr[lane + j * 64];
            const float4 rv = rr[lane + j * 64];
            ss += v.x * v.x + v.y * v.y + v.z * v.z + v.w * v.w;
            rs += rv.x + rv.y + rv.z + rv.w;
            wqr[lane + j * 64] = pack4(v);
        }
#pragma unroll
        for (int o = 32; o; o >>= 1) { ss += __shfl_xor(ss, o); rs += __shfl_xor(rs, o); }
        if (lane == 0) {
            w2p[n] = ss;
            rsump[n] = rs;
            // act = nc*D/(D + x2 + g), g = w2 - 2s + D*1e-7/rs -> rank by min g
            gbp[n] = ss + (1e-7f * (float)D_DIM) / rs;
        }
    }
}

// 128x128 tile, BK=128, 4 waves each own a 64x64 quadrant. LDS = 32 KB.
__device__ __forceinline__ void gemm_tile(int tile, const signed char* xq, const signed char* wq,
                                          const float* gbp, unsigned char* res, float* tminp,
                                          int4* As, int4* Bs, int t) {
    const int lane = t & 63, wave = t >> 6;
    const int q = lane >> 4, ln = lane & 15;
    const int wm = wave >> 1, wn = wave & 1;
    const int mt = tile & 63;   // 64 m-tiles (B/128)
    const int nt = tile >> 6;   // 32 n-tiles (N/128)
    const int m0 = mt * 128, n0 = nt * 128;

    intv4 acc[4][4];
#pragma unroll
    for (int i = 0; i < 4; ++i)
#pragma unroll
        for (int j = 0; j < 4; ++j) acc[i][j] = (intv4){0, 0, 0, 0};

    int rr[4], jj[4];
#pragma unroll
    for (int s = 0; s < 4; ++s) {
        int L = t + s * 256;
        rr[s] = L >> 3; jj[s] = (L & 7) ^ (rr[s] & 7);
    }

    const signed char* Ap = xq + (size_t)m0 * D_DIM;
    const signed char* Bp = wq + (size_t)n0 * D_DIM;
    for (int kt = 0; kt < 8; ++kt) {
        const int k0 = kt * 128;
#pragma unroll
        for (int s = 0; s < 4; ++s) {
            async16((char*)As + (t + s * 256) * 16, Ap + (size_t)rr[s] * D_DIM + k0 + jj[s] * 16);
            async16((char*)Bs + (t + s * 256) * 16, Bp + (size_t)rr[s] * D_DIM + k0 + jj[s] * 16);
        }
        __syncthreads();
#pragma unroll
        for (int ks = 0; ks < 2; ++ks) {
            intv4 a[4], b[4];
#pragma unroll
            for (int i = 0; i < 4; ++i) {
                int r = wm * 64 + i * 16 + ln;
                int jx = (ks * 4 + q) ^ (r & 7);
                a[i] = *(const intv4*)((const char*)As + (r * 8 + jx) * 16);
            }
#pragma unroll
            for (int j = 0; j < 4; ++j) {
                int r = wn * 64 + j * 16 + ln;
                int jx = (ks * 4 + q) ^ (r & 7);
                b[j] = *(const intv4*)((const char*)Bs + (r * 8 + jx) * 16);
            }
#pragma unroll
            for (int i = 0; i < 4; ++i)
#pragma unroll
                for (int j = 0; j < 4; ++j)
                    acc[i][j] = __builtin_amdgcn_mfma_i32_16x16x64_i8(a[i], b[j], acc[i][j], 0, 0, 0);
        }
        __syncthreads();
    }

    // epilogue: g = gb[n] - 2*s/QS^2; per-(row, 64-col tile) f32 min + u8 residual (0.5 steps)
    float gbv[4];
#pragma unroll
    for (int jt = 0; jt < 4; ++jt) gbv[jt] = gbp[n0 + wn * 64 + jt * 16 + ln];
    const float cf = 2.0f * INV_QS2;
#pragma unroll
    for (int i = 0; i < 4; ++i) {
#pragma unroll
        for (int r = 0; r < 4; ++r) {
            const int m = m0 + wm * 64 + i * 16 + q * 4 + r;
            float g[4];
            float gmin = 3.4e38f;
#pragma unroll
            for (int jt = 0; jt < 4; ++jt) {
                g[jt] = gbv[jt] - cf * (float)acc[i][jt][r];
                gmin = fminf(gmin, g[jt]);
            }
#pragma unroll
            for (int o = 1; o < 16; o <<= 1) gmin = fminf(gmin, __shfl_xor(gmin, o));
            if (ln == 0) tminp[(size_t)m * 64 + nt * 2 + wn] = gmin;
#pragma unroll
            for (int jt = 0; jt < 4; ++jt) {
                int u = (int)rintf((g[jt] - gmin) * 2.0f);
                u = (u > 255) ? 255 : u;
                res[(size_t)m * N_DIM + n0 + wn * 64 + jt * 16 + ln] = (unsigned char)u;
            }
        }
    }
}

__device__ __forceinline__ void resolve_row(int b, const unsigned char* res, const float* tminp,
                                            const float* x2p, const float* x, const float* w,
                                            const float* w2p, const float* rsump, const float* ncp,
                                            int* win, int lane) {
    const float tv = tminp[(size_t)b * 64 + lane];   // lane = 64-col tile index
    float rowmin = tv;
#pragma unroll
    for (int o = 32; o; o >>= 1) rowmin = fminf(rowmin, __shfl_xor(rowmin, o));
    const float th = rowmin + MARGIN_G;
    const unsigned long long tmask = __ballot(tv <= th);
    const float x2v = x2p[b];

    int cnt = 0, myn = -1;
    float myg = 0.0f;
    unsigned long long tm = tmask;
    while (tm) {
        const int tt = __ffsll((long long)tm) - 1;
        tm &= tm - 1;
        const float tb = __shfl(tv, tt);
        const unsigned char rv = res[(size_t)b * N_DIM + tt * 64 + lane];
        const float g = tb + 0.5f * (float)rv;
        const bool c = (g <= th);
        cnt += __popcll(__ballot(c));
        if (c && myn < 0) { myn = tt * 64 + lane; myg = g; }
    }

    if (cnt == 1) {
        if (myn >= 0) {
            const float act = ncp[myn] * (float)D_DIM / ((float)D_DIM + x2v + myg);
            win[b] = (act >= ATc) ? myn : -1;
        }
    } else {
        const float4* xr = (const float4*)(x + (size_t)b * D_DIM);
        float4 xv[4];
#pragma unroll
        for (int j = 0; j < 4; ++j) xv[j] = xr[lane + j * 64];
        float best_act = -1.0f;
        int best_n = N_DIM;
        tm = tmask;
        while (tm) {
            const int tt = __ffsll((long long)tm) - 1;
            tm &= tm - 1;
            const float tb = __shfl(tv, tt);
            const unsigned char rv = res[(size_t)b * N_DIM + tt * 64 + lane];
            const float g = tb + 0.5f * (float)rv;
            unsigned long long cm = __ballot(g <= th);
            while (cm) {
                const int l = __ffsll((long long)cm) - 1;
                cm &= cm - 1;
                const int n = tt * 64 + l;
                const float4* wr = (const float4*)(w + (size_t)n * D_DIM);
                float p = 0.f;
#pragma unroll
                for (int j = 0; j < 4; ++j) {
                    const float4 wv = wr[lane + j * 64];
                    p += xv[j].x * wv.x + xv[j].y * wv.y + xv[j].z * wv.z + xv[j].w * wv.w;
                }
#pragma unroll
                for (int o = 32; o; o >>= 1) p += __shfl_xor(p, o);
                const float dist = x2v + w2p[n] - 2.0f * p;
                const float rs = rsump[n];
                const float dw = dist * rs * (1.0f / (float)D_DIM);
                const float a = rs * ncp[n] / (rs + dw + 1e-7f);
                if (a > best_act || (a == best_act && n < best_n)) { best_act = a; best_n = n; }
            }
        }
        if (lane == 0) win[b] = (best_act >= ATc) ? best_n : -1;
    }
}

struct FinalSmem {
    unsigned short list[B_DIM];
    int cnt;
    float smax[4], smin[4], ssum[4];
};

__device__ __forceinline__ void finalize_node(int n, const float* x, const float* w, const float* mavg,
                                              const int* win, float* out, FinalSmem* sf, int t) {
    const int lane = t & 63, wave = t >> 6;
    if (t == 0) sf->cnt = 0;
    __syncthreads();
    const int4* wp = (const int4*)win;
#pragma unroll
    for (int k = 0; k < 8; ++k) {
        const int4 v = wp[k * 256 + t];
        const int b0 = (k * 256 + t) * 4;
        if (v.x == n) sf->list[atomicAdd(&sf->cnt, 1)] = (unsigned short)(b0 + 0);
        if (v.y == n) sf->list[atomicAdd(&sf->cnt, 1)] = (unsigned short)(b0 + 1);
        if (v.z == n) sf->list[atomicAdd(&sf->cnt, 1)] = (unsigned short)(b0 + 2);
        if (v.w == n) sf->list[atomicAdd(&sf->cnt, 1)] = (unsigned short)(b0 + 3);
    }
    __syncthreads();
    const int c = sf->cnt;
    float4 s = {0.f, 0.f, 0.f, 0.f};
    for (int e = 0; e < c; ++e) {
        const float4 xv = ((const float4*)(x + (size_t)sf->list[e] * D_DIM))[t];
        s.x += xv.x; s.y += xv.y; s.z += xv.z; s.w += xv.w;
    }
    const float has = (c > 0) ? 1.0f : 0.0f;
    const float invc = 1.0f / fmaxf((float)c, 1.0f);
    const size_t base4 = (size_t)n * (D_DIM / 4);
    const float4 wv = ((const float4*)w)[base4 + t];
    const float4 mk = ((const float4*)mavg)[base4 + t];
    float4 ms, mv;
    ms.x = s.x * invc; ms.y = s.y * invc; ms.z = s.z * invc; ms.w = s.w * invc;
    mv.x = EMAc * fabsf(ms.x - wv.x) + (1.0f - EMAc) * mk.x;
    mv.y = EMAc * fabsf(ms.y - wv.y) + (1.0f - EMAc) * mk.y;
    mv.z = EMAc * fabsf(ms.z - wv.z) + (1.0f - EMAc) * mk.z;
    mv.w = EMAc * fabsf(ms.w - wv.w) + (1.0f - EMAc) * mk.w;
    float lmax = fmaxf(fmaxf(mv.x, mv.y), fmaxf(mv.z, mv.w));
    float lmin = fminf(fminf(mv.x, mv.y), fminf(mv.z, mv.w));
    float lsum = mv.x + mv.y + mv.z + mv.w;
#pragma unroll
    for (int o = 32; o; o >>= 1) {
        lmax = fmaxf(lmax, __shfl_xor(lmax, o));
        lmin = fminf(lmin, __shfl_xor(lmin, o));
        lsum += __shfl_xor(lsum, o);
    }
    if (lane == 0) { sf->smax[wave] = lmax; sf->smin[wave] = lmin; sf->ssum[wave] = lsum; }
    __syncthreads();
    const float mx = fmaxf(fmaxf(sf->smax[0], sf->smax[1]), fmaxf(sf->smax[2], sf->smax[3]));
    const float mn = fminf(fminf(sf->smin[0], sf->smin[1]), fminf(sf->smin[2], sf->smin[3]));
    const float avg = (sf->ssum[0] + sf->ssum[1] + sf->ssum[2] + sf->ssum[3]) * (1.0f / (float)D_DIM);
    const float scale = 0.5f * (mx - mn);       // EPS_DS*(mx-mn)
    const float invs = (scale > 0.0f) ? 1.0f / scale : 0.0f;
    float4 relv;
    if (scale > 0.0f) {
        relv.x = 1.0f / (1.0f + __expf((mv.x - avg) * invs));
        relv.y = 1.0f / (1.0f + __expf((mv.y - avg) * invs));
        relv.z = 1.0f / (1.0f + __expf((mv.z - avg) * invs));
        relv.w = 1.0f / (1.0f + __expf((mv.w - avg) * invs));
    } else {
        relv.x = relv.y = relv.z = relv.w = 1.0f;
    }
    float4* o0 = (float4*)out;
    float4 r0, r1, r2;
    r0.x = ms.x * has; r0.y = ms.y * has; r0.z = ms.z * has; r0.w = ms.w * has;
    r1.x = (wv.x + LRc * (ms.x - wv.x)) * has;
    r1.y = (wv.y + LRc * (ms.y - wv.y)) * has;
    r1.z = (wv.z + LRc * (ms.z - wv.z)) * has;
    r1.w = (wv.w + LRc * (ms.w - wv.w)) * has;
    r2.x = relv.x * has; r2.y = relv.y * has; r2.z = relv.z * has; r2.w = relv.w * has;
    o0[base4 + t] = r0;
    o0[ND / 4 + base4 + t] = r1;
    o0[2 * (ND / 4) + base4 + t] = r2;
}

// ======================= fused cooperative kernel (32 KB LDS union) =======================

union SMem {
    struct { int4 As[1024]; int4 Bs[1024]; } g;   // 32 KB
    FinalSmem f;                                  // ~16.1 KB
};

__global__ __launch_bounds__(256, 2) void som_fused(
        const float* __restrict__ x, const float* __restrict__ w,
        const float* __restrict__ rel, const float* __restrict__ mavg,
        const float* __restrict__ ncp, float* __restrict__ out,
        signed char* __restrict__ xq, signed char* __restrict__ wq,
        float* __restrict__ x2p, float* __restrict__ w2p,
        float* __restrict__ rsump, float* __restrict__ gbp,
        unsigned char* __restrict__ res, float* __restrict__ tminp,
        int* __restrict__ win) {
    cg::grid_group grid = cg::this_grid();
    __shared__ SMem sm;
    const int t = threadIdx.x;
    const int lane = t & 63, wave = t >> 6;

    for (int it = 0; it < 6; ++it)
        prep_row(((blockIdx.x + it * NBLK) << 2) + wave, x, w, rel, xq, wq, x2p, w2p, rsump, gbp, lane);

    __threadfence(); grid.sync(); __threadfence();

    for (int it = 0; it < 4; ++it)
        gemm_tile(blockIdx.x + it * NBLK, xq, wq, gbp, res, tminp, sm.g.As, sm.g.Bs, t);

    __threadfence(); grid.sync(); __threadfence();

    for (int it = 0; it < 4; ++it)
        resolve_row(((blockIdx.x + it * NBLK) << 2) + wave, res, tminp, x2p, x, w, w2p, rsump, ncp, win, lane);

    __threadfence(); grid.sync(); __threadfence();

    for (int it = 0; it < 8; ++it) {
        __syncthreads();   // protect LDS reuse across iterations
        finalize_node(blockIdx.x + it * NBLK, x, w, mavg, win, out, &sm.f, t);
    }
}

// ======================= fallback standalone kernels (proven R7 path) =======================

__global__ __launch_bounds__(256) void prep_k(const float* __restrict__ x, const float* __restrict__ w,
                                              const float* __restrict__ rel,
                                              signed char* __restrict__ xq, signed char* __restrict__ wq,
                                              float* __restrict__ x2p, float* __restrict__ w2p,
                                              float* __restrict__ rsump, float* __restrict__ gbp) {
    const int lane = threadIdx.x & 63, wave = threadIdx.x >> 6;
    prep_row((blockIdx.x << 2) + wave, x, w, rel, xq, wq, x2p, w2p, rsump, gbp, lane);
}

__global__ __launch_bounds__(256) void gemm_k(const signed char* __restrict__ xq,
                                              const signed char* __restrict__ wq,
                                              const float* __restrict__ gbp,
                                              unsigned char* __restrict__ res,
                                              float* __restrict__ tminp) {
    __shared__ int4 As[1024];
    __shared__ int4 Bs[1024];
    gemm_tile(blockIdx.x, xq, wq, gbp, res, tminp, As, Bs, threadIdx.x);
}

__global__ __launch_bounds__(256) void resolve_k(const unsigned char* __restrict__ res,
                                                 const float* __restrict__ tminp,
                                                 const float* __restrict__ x2p,
                                                 const float* __restrict__ x, const float* __restrict__ w,
                                                 const float* __restrict__ w2p, const float* __restrict__ rsump,
                                                 const float* __restrict__ ncp,
                                                 int* __restrict__ win) {
    const int lane = threadIdx.x & 63, wave = threadIdx.x >> 6;
    resolve_row((blockIdx.x << 2) + wave, res, tminp, x2p, x, w, w2p, rsump, ncp, win, lane);
}

__global__ __launch_bounds__(256) void finalize_k(const float* __restrict__ x, const float* __restrict__ w,
                                                  const float* __restrict__ mavg, const int* __restrict__ win,
                                                  float* __restrict__ out) {
    __shared__ FinalSmem sf;
    finalize_node(blockIdx.x, x, w, mavg, win, out, &sf, threadIdx.x);
}

extern "C" void kernel_launch(void* const* d_in, const int* in_sizes, int n_in,
                              void* d_out, int out_size, void* d_ws, size_t ws_size,
                              hipStream_t stream) {
    const float* x    = (const float*)d_in[0];
    const float* w    = (const float*)d_in[1];
    const float* rel  = (const float*)d_in[2];
    const float* mavg = (const float*)d_in[3];
    const float* nc   = (const float*)d_in[4];
    float* out = (float*)d_out;

    char* p = (char*)d_ws;
    size_t off = 0;
    auto take = [&](size_t bytes) -> char* {
        char* r = p + off;
        off += (bytes + 255) & ~(size_t)255;
        return r;
    };
    signed char* xq = (signed char*)take((size_t)B_DIM * D_DIM);
    signed char* wq = (signed char*)take((size_t)N_DIM * D_DIM);
    float* x2       = (float*)take((size_t)B_DIM * 4);
    float* w2       = (float*)take((size_t)N_DIM * 4);
    float* rsum     = (float*)take((size_t)N_DIM * 4);
    float* gb       = (float*)take((size_t)N_DIM * 4);
    unsigned char* res = (unsigned char*)take((size_t)B_DIM * N_DIM);
    float* tminp    = (float*)take((size_t)B_DIM * 64 * 4);
    int* win        = (int*)take((size_t)B_DIM * 4);

    void* kargs[] = { (void*)&x, (void*)&w, (void*)&rel, (void*)&mavg, (void*)&nc, (void*)&out,
                      (void*)&xq, (void*)&wq, (void*)&x2, (void*)&w2, (void*)&rsum, (void*)&gb,
                      (void*)&res, (void*)&tminp, (void*)&win };
    hipError_t err = hipLaunchCooperativeKernel((const void*)som_fused, dim3(NBLK), dim3(256),
                                                kargs, 0, stream);
    if (err != hipSuccess) {
        // fallback: proven 4-kernel pipeline
        prep_k<<<(B_DIM + N_DIM) / 4, 256, 0, stream>>>(x, w, rel, xq, wq, x2, w2, rsum, gb);
        gemm_k<<<2048, 256, 0, stream>>>(xq, wq, gb, res, tminp);
        resolve_k<<<B_DIM / 4, 256, 0, stream>>>(res, tminp, x2, x, w, w2, rsum, nc, win);
        finalize_k<<<N_DIM, 256, 0, stream>>>(x, w, mavg, win, out);
    }
}

// Round 10
// 205.351 us; speedup vs baseline: 3.2225x; 3.2225x over previous
//
#include <hip/hip_runtime.h>
#include <stdint.h>

// R10: proven R7 4-kernel pipeline (coop fusion dead — R9: fence/sync storms, 555us).
// Change vs R7: gemm epilogue stores 4-bit residuals packed 4-per-u16 (same-lane pack,
// no shuffles): 32 u16 stores/thread vs 128 byte stores; WRITE 34->18 MB.

#define B_DIM 8192
#define D_DIM 1024
#define N_DIM 4096
#define ND ((size_t)N_DIM * D_DIM)
#define LRc 0.02f
#define ATc 0.3f
#define EMAc (0.02f * 0.1f)   // LR*DSBETA = 0.002
#define QS 32.0f              // i8 quant scale
#define INV_QS2 (1.0f / (QS * QS))
#define MARGIN_G 10.0f        // candidate window in g-units (~9 sigma of i8 error; +0.5 nib slack in test)

typedef int intv4 __attribute__((ext_vector_type(4)));

__device__ __forceinline__ void async16(void* lds, const void* g) {
    __builtin_amdgcn_global_load_lds((const __attribute__((address_space(1))) void*)g,
                                     (__attribute__((address_space(3))) void*)lds, 16, 0, 0);
}

__device__ __forceinline__ int q8(float v) {
    return (int)rintf(fminf(fmaxf(v * QS, -127.0f), 127.0f));
}

__device__ __forceinline__ unsigned pack4(float4 v) {
    return (unsigned)(q8(v.x) & 255) | ((unsigned)(q8(v.y) & 255) << 8)
         | ((unsigned)(q8(v.z) & 255) << 16) | ((unsigned)(q8(v.w) & 255) << 24);
}

// ---------------- prep: quantize x/w to i8, norms, gb. One wave per row. ----------------
__global__ __launch_bounds__(256) void prep_k(const float* __restrict__ x, const float* __restrict__ w,
                                              const float* __restrict__ rel,
                                              signed char* __restrict__ xq, signed char* __restrict__ wq,
                                              float* __restrict__ x2p, float* __restrict__ w2p,
                                              float* __restrict__ rsump, float* __restrict__ gbp) {
    const int lane = threadIdx.x & 63, wave = threadIdx.x >> 6;
    const int row = (blockIdx.x << 2) + wave;
    if (row < B_DIM) {
        const float4* xr = (const float4*)(x + (size_t)row * D_DIM);
        unsigned* xqr = (unsigned*)(xq + (size_t)row * D_DIM);
        float ss = 0.f;
#pragma unroll
        for (int j = 0; j < 4; ++j) {
            const float4 v = xr[lane + j * 64];
            ss += v.x * v.x + v.y * v.y + v.z * v.z + v.w * v.w;
            xqr[lane + j * 64] = pack4(v);
        }
#pragma unroll
        for (int o = 32; o; o >>= 1) ss += __shfl_xor(ss, o);
        if (lane == 0) x2p[row] = ss;
    } else {
        const int n = row - B_DIM;
        const float4* wr = (const float4*)(w + (size_t)n * D_DIM);
        const float4* rr = (const float4*)(rel + (size_t)n * D_DIM);
        unsigned* wqr = (unsigned*)(wq + (size_t)n * D_DIM);
        float ss = 0.f, rs = 0.f;
#pragma unroll
        for (int j = 0; j < 4; ++j) {
            const float4 v = wr[lane + j * 64];
            const float4 rv = rr[lane + j * 64];
            ss += v.x * v.x + v.y * v.y + v.z * v.z + v.w * v.w;
            rs += rv.x + rv.y + rv.z + rv.w;
            wqr[lane + j * 64] = pack4(v);
        }
#pragma unroll
        for (int o = 32; o; o >>= 1) { ss += __shfl_xor(ss, o); rs += __shfl_xor(rs, o); }
        if (lane == 0) {
            w2p[n] = ss;
            rsump[n] = rs;
            // act = nc*D/(D + x2 + g), g = w2 - 2s + D*1e-7/rs -> rank by min g
            gbp[n] = ss + (1e-7f * (float)D_DIM) / rs;
        }
    }
}

// ---------------- i8 GEMM -> per-64col tile min (f32) + 4-bit residuals ----------------
// 128x256 block tile, BK=128, 4 waves each own a 64x128 quadrant (4x8 of 16x16x64 MFMA).
__global__ __launch_bounds__(256, 2) void gemm_k(const signed char* __restrict__ xq,
                                                 const signed char* __restrict__ wq,
                                                 const float* __restrict__ gbp,
                                                 unsigned short* __restrict__ resq,
                                                 float* __restrict__ tminp) {
    __shared__ int4 As[1024];   // 128 rows x 128 B
    __shared__ int4 Bs[2048];   // 256 rows x 128 B
    const int t = threadIdx.x;
    const int mt = blockIdx.x & 63;   // 64 m-tiles (B/128)
    const int nt = blockIdx.x >> 6;   // 16 n-tiles (N/256)
    const int m0 = mt * 128, n0 = nt * 256;
    const int lane = t & 63, wave = t >> 6;
    const int q = lane >> 4, ln = lane & 15;
    const int wm = wave >> 1, wn = wave & 1;

    intv4 acc[4][8];
#pragma unroll
    for (int i = 0; i < 4; ++i)
#pragma unroll
        for (int j = 0; j < 8; ++j) acc[i][j] = (intv4){0, 0, 0, 0};

    // staging swizzle: slot L holds global (row r=L>>3, chunk c=(L&7)^(r&7)); read pos jx=k^(r&7)
    int rrA[4], jjA[4], rrB[8], jjB[8];
#pragma unroll
    for (int s = 0; s < 4; ++s) {
        int L = t + s * 256;
        rrA[s] = L >> 3; jjA[s] = (L & 7) ^ (rrA[s] & 7);
    }
#pragma unroll
    for (int s = 0; s < 8; ++s) {
        int L = t + s * 256;
        rrB[s] = L >> 3; jjB[s] = (L & 7) ^ (rrB[s] & 7);
    }

    const signed char* Ap = xq + (size_t)m0 * D_DIM;
    const signed char* Bp = wq + (size_t)n0 * D_DIM;
    for (int kt = 0; kt < 8; ++kt) {
        const int k0 = kt * 128;
#pragma unroll
        for (int s = 0; s < 4; ++s)
            async16((char*)As + (t + s * 256) * 16, Ap + (size_t)rrA[s] * D_DIM + k0 + jjA[s] * 16);
#pragma unroll
        for (int s = 0; s < 8; ++s)
            async16((char*)Bs + (t + s * 256) * 16, Bp + (size_t)rrB[s] * D_DIM + k0 + jjB[s] * 16);
        __syncthreads();
#pragma unroll
        for (int ks = 0; ks < 2; ++ks) {
            intv4 a[4], b[8];
#pragma unroll
            for (int i = 0; i < 4; ++i) {
                int r = wm * 64 + i * 16 + ln;
                int jx = (ks * 4 + q) ^ (r & 7);
                a[i] = *(const intv4*)((const char*)As + (r * 8 + jx) * 16);
            }
#pragma unroll
            for (int j = 0; j < 8; ++j) {
                int r = wn * 128 + j * 16 + ln;
                int jx = (ks * 4 + q) ^ (r & 7);
                b[j] = *(const intv4*)((const char*)Bs + (r * 8 + jx) * 16);
            }
#pragma unroll
            for (int i = 0; i < 4; ++i)
#pragma unroll
                for (int j = 0; j < 8; ++j)
                    acc[i][j] = __builtin_amdgcn_mfma_i32_16x16x64_i8(a[i], b[j], acc[i][j], 0, 0, 0);
        }
        __syncthreads();
    }

    // epilogue: g = gb[n] - 2*s/QS^2; per-(row, 64-tile) f32 min + 4-bit residual (step 1.0)
    // resq layout: u16 slot = tile64*16 + (n&15), nibble = (n>>4)&3; 1024 u16 per row.
    float gbv[8];
#pragma unroll
    for (int j = 0; j < 8; ++j) gbv[j] = gbp[n0 + wn * 128 + j * 16 + ln];
    const float cf = 2.0f * INV_QS2;
    const int tileA = nt * 4 + wn * 2;        // 64-col tile indices this wave covers
#pragma unroll
    for (int i = 0; i < 4; ++i) {
#pragma unroll
        for (int r = 0; r < 4; ++r) {
            const int m = m0 + wm * 64 + i * 16 + q * 4 + r;
            float g[8];
            float mnA = 3.4e38f, mnB = 3.4e38f;
#pragma unroll
            for (int j = 0; j < 8; ++j) {
                g[j] = gbv[j] - cf * (float)acc[i][j][r];
                if (j < 4) mnA = fminf(mnA, g[j]); else mnB = fminf(mnB, g[j]);
            }
#pragma unroll
            for (int o = 1; o < 16; o <<= 1) {
                mnA = fminf(mnA, __shfl_xor(mnA, o));
                mnB = fminf(mnB, __shfl_xor(mnB, o));
            }
            if (ln == 0) {
                tminp[(size_t)m * 64 + tileA + 0] = mnA;
                tminp[(size_t)m * 64 + tileA + 1] = mnB;
            }
            unsigned uA = 0, uB = 0;
#pragma unroll
            for (int j = 0; j < 4; ++j) {
                int a4 = (int)rintf(g[j] - mnA);
                a4 = (a4 > 15) ? 15 : a4;
                uA |= (unsigned)a4 << (4 * j);
                int b4 = (int)rintf(g[j + 4] - mnB);
                b4 = (b4 > 15) ? 15 : b4;
                uB |= (unsigned)b4 << (4 * j);
            }
            unsigned short* rq = resq + (size_t)m * 1024;
            rq[(tileA + 0) * 16 + ln] = (unsigned short)uA;
            rq[(tileA + 1) * 16 + ln] = (unsigned short)uB;
        }
    }
}

// ---------------- resolve winner per row: tile-pruned; exact f32 re-rank only on ties ----------------
__global__ __launch_bounds__(256) void resolve_k(const unsigned short* __restrict__ resq,
                                                 const float* __restrict__ tminp,
                                                 const float* __restrict__ x2p,
                                                 const float* __restrict__ x, const float* __restrict__ w,
                                                 const float* __restrict__ w2p, const float* __restrict__ rsump,
                                                 const float* __restrict__ ncp,
                                                 int* __restrict__ win) {
    const int lane = threadIdx.x & 63, wave = threadIdx.x >> 6;
    const int b = (blockIdx.x << 2) + wave;
    const float tv = tminp[(size_t)b * 64 + lane];   // lane = 64-col tile index
    float rowmin = tv;
#pragma unroll
    for (int o = 32; o; o >>= 1) rowmin = fminf(rowmin, __shfl_xor(rowmin, o));
    const float th = rowmin + MARGIN_G;
    const float thq = th + 0.5f;                     // +0.5 nibble-quant slack
    const unsigned long long tmask = __ballot(tv <= th);
    const float x2v = x2p[b];
    const unsigned short* rrow = resq + (size_t)b * 1024;
    const int nibsh = (lane >> 4) * 4;

    int cnt = 0, myn = -1;
    float myg = 0.0f;
    unsigned long long tm = tmask;
    while (tm) {
        const int tt = __ffsll((long long)tm) - 1;
        tm &= tm - 1;
        const float tb = __shfl(tv, tt);
        const unsigned short pv = rrow[tt * 16 + (lane & 15)];
        const float g = tb + (float)((pv >> nibsh) & 15);
        const bool c = (g <= thq);
        cnt += __popcll(__ballot(c));
        if (c && myn < 0) { myn = tt * 64 + lane; myg = g; }
    }

    if (cnt == 1) {
        if (myn >= 0) {
            const float act = ncp[myn] * (float)D_DIM / ((float)D_DIM + x2v + myg);
            win[b] = (act >= ATc) ? myn : -1;
        }
    } else {
        // exact f32 re-rank of all candidates
        const float4* xr = (const float4*)(x + (size_t)b * D_DIM);
        float4 xv[4];
#pragma unroll
        for (int j = 0; j < 4; ++j) xv[j] = xr[lane + j * 64];
        float best_act = -1.0f;
        int best_n = N_DIM;
        tm = tmask;
        while (tm) {
            const int tt = __ffsll((long long)tm) - 1;
            tm &= tm - 1;
            const float tb = __shfl(tv, tt);
            const unsigned short pv = rrow[tt * 16 + (lane & 15)];
            const float g = tb + (float)((pv >> nibsh) & 15);
            unsigned long long cm = __ballot(g <= thq);
            while (cm) {
                const int l = __ffsll((long long)cm) - 1;
                cm &= cm - 1;
                const int n = tt * 64 + l;
                const float4* wr = (const float4*)(w + (size_t)n * D_DIM);
                float p = 0.f;
#pragma unroll
                for (int j = 0; j < 4; ++j) {
                    const float4 wv = wr[lane + j * 64];
                    p += xv[j].x * wv.x + xv[j].y * wv.y + xv[j].z * wv.z + xv[j].w * wv.w;
                }
#pragma unroll
                for (int o = 32; o; o >>= 1) p += __shfl_xor(p, o);
                const float dist = x2v + w2p[n] - 2.0f * p;
                const float rs = rsump[n];
                const float dw = dist * rs * (1.0f / (float)D_DIM);
                const float a = rs * ncp[n] / (rs + dw + 1e-7f);
                if (a > best_act || (a == best_act && n < best_n)) { best_act = a; best_n = n; }
            }
        }
        if (lane == 0) win[b] = (best_act >= ATc) ? best_n : -1;
    }
}

// ---------------- per-node gather + update + outputs ----------------
__global__ __launch_bounds__(256) void finalize_k(const float* __restrict__ x, const float* __restrict__ w,
                                                  const float* __restrict__ mavg, const int* __restrict__ win,
                                                  float* __restrict__ out) {
    const int n = blockIdx.x, t = threadIdx.x;
    __shared__ unsigned short list[B_DIM];
    __shared__ int cnt;
    __shared__ float smax[4], smin[4], ssum[4];
    if (t == 0) cnt = 0;
    __syncthreads();
    const int4* wp = (const int4*)win;
#pragma unroll
    for (int k = 0; k < 8; ++k) {
        const int4 v = wp[k * 256 + t];
        const int b0 = (k * 256 + t) * 4;
        if (v.x == n) list[atomicAdd(&cnt, 1)] = (unsigned short)(b0 + 0);
        if (v.y == n) list[atomicAdd(&cnt, 1)] = (unsigned short)(b0 + 1);
        if (v.z == n) list[atomicAdd(&cnt, 1)] = (unsigned short)(b0 + 2);
        if (v.w == n) list[atomicAdd(&cnt, 1)] = (unsigned short)(b0 + 3);
    }
    __syncthreads();
    const int c = cnt;
    float4 s = {0.f, 0.f, 0.f, 0.f};
    for (int e = 0; e < c; ++e) {
        const float4 xv = ((const float4*)(x + (size_t)list[e] * D_DIM))[t];
        s.x += xv.x; s.y += xv.y; s.z += xv.z; s.w += xv.w;
    }
    const float has = (c > 0) ? 1.0f : 0.0f;
    const float invc = 1.0f / fmaxf((float)c, 1.0f);
    const size_t base4 = (size_t)n * (D_DIM / 4);
    const float4 wv = ((const float4*)w)[base4 + t];
    const float4 mk = ((const float4*)mavg)[base4 + t];
    float4 ms, mv;
    ms.x = s.x * invc; ms.y = s.y * invc; ms.z = s.z * invc; ms.w = s.w * invc;
    mv.x = EMAc * fabsf(ms.x - wv.x) + (1.0f - EMAc) * mk.x;
    mv.y = EMAc * fabsf(ms.y - wv.y) + (1.0f - EMAc) * mk.y;
    mv.z = EMAc * fabsf(ms.z - wv.z) + (1.0f - EMAc) * mk.z;
    mv.w = EMAc * fabsf(ms.w - wv.w) + (1.0f - EMAc) * mk.w;
    float lmax = fmaxf(fmaxf(mv.x, mv.y), fmaxf(mv.z, mv.w));
    float lmin = fminf(fminf(mv.x, mv.y), fminf(mv.z, mv.w));
    float lsum = mv.x + mv.y + mv.z + mv.w;
#pragma unroll
    for (int o = 32; o; o >>= 1) {
        lmax = fmaxf(lmax, __shfl_xor(lmax, o));
        lmin = fminf(lmin, __shfl_xor(lmin, o));
        lsum += __shfl_xor(lsum, o);
    }
    const int wave = t >> 6, lane = t & 63;
    if (lane == 0) { smax[wave] = lmax; smin[wave] = lmin; ssum[wave] = lsum; }
    __syncthreads();
    const float mx = fmaxf(fmaxf(smax[0], smax[1]), fmaxf(smax[2], smax[3]));
    const float mn = fminf(fminf(smin[0], smin[1]), fminf(smin[2], smin[3]));
    const float avg = (ssum[0] + ssum[1] + ssum[2] + ssum[3]) * (1.0f / (float)D_DIM);
    const float scale = 0.5f * (mx - mn);       // EPS_DS*(mx-mn)
    const float invs = (scale > 0.0f) ? 1.0f / scale : 0.0f;
    float4 relv;
    if (scale > 0.0f) {
        relv.x = 1.0f / (1.0f + __expf((mv.x - avg) * invs));
        relv.y = 1.0f / (1.0f + __expf((mv.y - avg) * invs));
        relv.z = 1.0f / (1.0f + __expf((mv.z - avg) * invs));
        relv.w = 1.0f / (1.0f + __expf((mv.w - avg) * invs));
    } else {
        relv.x = relv.y = relv.z = relv.w = 1.0f;
    }
    float4* o0 = (float4*)out;
    float4 r0, r1, r2;
    r0.x = ms.x * has; r0.y = ms.y * has; r0.z = ms.z * has; r0.w = ms.w * has;
    r1.x = (wv.x + LRc * (ms.x - wv.x)) * has;
    r1.y = (wv.y + LRc * (ms.y - wv.y)) * has;
    r1.z = (wv.z + LRc * (ms.z - wv.z)) * has;
    r1.w = (wv.w + LRc * (ms.w - wv.w)) * has;
    r2.x = relv.x * has; r2.y = relv.y * has; r2.z = relv.z * has; r2.w = relv.w * has;
    o0[base4 + t] = r0;
    o0[ND / 4 + base4 + t] = r1;
    o0[2 * (ND / 4) + base4 + t] = r2;
}

extern "C" void kernel_launch(void* const* d_in, const int* in_sizes, int n_in,
                              void* d_out, int out_size, void* d_ws, size_t ws_size,
                              hipStream_t stream) {
    const float* x    = (const float*)d_in[0];
    const float* w    = (const float*)d_in[1];
    const float* rel  = (const float*)d_in[2];
    const float* mavg = (const float*)d_in[3];
    const float* nc   = (const float*)d_in[4];
    float* out = (float*)d_out;

    char* p = (char*)d_ws;
    size_t off = 0;
    auto take = [&](size_t bytes) -> char* {
        char* r = p + off;
        off += (bytes + 255) & ~(size_t)255;
        return r;
    };
    signed char* xq = (signed char*)take((size_t)B_DIM * D_DIM);
    signed char* wq = (signed char*)take((size_t)N_DIM * D_DIM);
    float* x2       = (float*)take((size_t)B_DIM * 4);
    float* w2       = (float*)take((size_t)N_DIM * 4);
    float* rsum     = (float*)take((size_t)N_DIM * 4);
    float* gb       = (float*)take((size_t)N_DIM * 4);
    unsigned short* resq = (unsigned short*)take((size_t)B_DIM * 1024 * 2);  // 4-bit/node
    float* tminp    = (float*)take((size_t)B_DIM * 64 * 4);
    int* win        = (int*)take((size_t)B_DIM * 4);

    prep_k<<<(B_DIM + N_DIM) / 4, 256, 0, stream>>>(x, w, rel, xq, wq, x2, w2, rsum, gb);
    gemm_k<<<1024, 256, 0, stream>>>(xq, wq, gb, resq, tminp);
    resolve_k<<<B_DIM / 4, 256, 0, stream>>>(resq, tminp, x2, x, w, w2, rsum, nc, win);
    finalize_k<<<N_DIM, 256, 0, stream>>>(x, w, mavg, win, out);
}